// Round 17
// baseline (136.973 us; speedup 1.0000x reference)
//
#include <hip/hip_runtime.h>
#include <stdint.h>

#define B_ 8
#define C_ 32
#define N_ 4096
#define KOUT 9

// mode-0 legacy (tiny workspace) params
#define RPB 8
#define TPB 512

// mode-1 (MFMA prefilter) params
#define RPB4 64     // rows per block; wave w verifies rows 8w..8w+7
#define TPB3 512    // 8 waves; wave w scans j in [512w, 512w+512)

// bf16 bound slack: |d_exact - d_mfma| <= (2u+u^2)*(si+sj), u=2^-8 -> 0.00787
// SLC2 = 1.5x margin; SLA2 covers f32 combine rounding + denormal flush.
// R16 reorder (si hoisted) perturbs bounds ~1e-5 << guaranteed margin.
#define SLC2 0.012f
#define SLA2 0.004f

// ws layout (float units): [sq: B*N][xbf u32: B*N*16][xT f32: B*N*32]
// xT (R12 lesson): contiguous 128B gather = 2 cache lines/candidate.
#define SQ_FLOATS   (B_ * N_)
#define XP_OFF_U32  (SQ_FLOATS)
#define XT_OFF_F32  (SQ_FLOATS + B_ * 16 * N_)
#define NEED_XT_B   ((size_t)(XT_OFF_F32 + B_ * N_ * C_) * 4)   // 6,422,528

typedef unsigned long long u64;
typedef unsigned int u32;
typedef __attribute__((ext_vector_type(8))) short short8;   // 8 bf16 (4 VGPRs)
typedef __attribute__((ext_vector_type(4))) float f32x4;

// monotone float->uint mapping: a<b <=> fkey(a)<fkey(b) (exact keys only)
__device__ __forceinline__ u32 fkey(float f) {
    u32 u = __float_as_uint(f);
    return u ^ (u32)((((int)u) >> 31) | 0x80000000u);
}

// f32 -> bf16 RNE (no NaN/Inf in data)
__device__ __forceinline__ u32 rne_bf16(float f) {
    u32 u = __float_as_uint(f);
    return (u + 0x7fffu + ((u >> 16) & 1u)) >> 16;
}

// branchless insert keep-6-smallest — exact fallback only
__device__ __forceinline__ void ins6(u64 k, u64& L0, u64& L1, u64& L2,
                                     u64& L3, u64& L4, u64& L5) {
    bool lt0 = k < L0, lt1 = k < L1, lt2 = k < L2,
         lt3 = k < L3, lt4 = k < L4, lt5 = k < L5;
    L5 = lt4 ? L4 : (lt5 ? k : L5);
    L4 = lt3 ? L3 : (lt4 ? k : L4);
    L3 = lt2 ? L2 : (lt3 ? k : L3);
    L2 = lt1 ? L1 : (lt2 ? k : L2);
    L1 = lt0 ? L0 : (lt1 ? k : L1);
    L0 = lt0 ? k : L0;
}

// ---------------- mode-0: proven R13 pipeline (unchanged) ----------------

__global__ __launch_bounds__(256) void sq_kernel(const float* __restrict__ x,
                                                 float* __restrict__ sq) {
#pragma clang fp contract(off)
    int gid = blockIdx.x * 256 + threadIdx.x;
    int b = gid >> 12, n = gid & (N_ - 1);
    const float* xp = x + (size_t)b * (C_ * N_) + n;
    float w[C_];
#pragma unroll
    for (int c = 0; c < C_; ++c) { float v = xp[(size_t)c * N_]; w[c] = v * v; }
    float r[8];
#pragma unroll
    for (int j = 0; j < 8; ++j) r[j] = w[j];
#pragma unroll
    for (int i = 8; i < 32; i += 8) {
#pragma unroll
        for (int j = 0; j < 8; ++j) r[j] = r[j] + w[i + j];
    }
    sq[gid] = ((r[0] + r[1]) + (r[2] + r[3])) + ((r[4] + r[5]) + (r[6] + r[7]));
}

__global__ __launch_bounds__(TPB, 4) void knn_kernel_old(const float* __restrict__ x,
                                                         const float* __restrict__ sq,
                                                         int* __restrict__ out) {
#pragma clang fp contract(off)
    __shared__ float cenL[C_][RPB];
    __shared__ float mL[RPB][8][64];
    __shared__ u64 bufL[RPB][64];
    __shared__ u32 cntL[RPB];
    __shared__ float tL[RPB];

    const int tid = threadIdx.x;
    const int b = blockIdx.x & 7;
    const int i0 = (blockIdx.x >> 3) * RPB;
    const float* xb = x + (size_t)b * (C_ * N_);
    const float* sqb = sq + b * N_;

    if (tid < RPB * C_) {
        int r = tid & (RPB - 1), c = tid >> 3;
        cenL[c][r] = xb[(size_t)c * N_ + (i0 + r)];
    }
    __syncthreads();

    float acc[RPB][8];
#pragma unroll
    for (int r = 0; r < RPB; ++r)
#pragma unroll
        for (int q = 0; q < 8; ++q) acc[r][q] = 0.0f;

    const int j0 = tid << 2;
#pragma unroll 1
    for (int cc = 0; cc < C_; cc += 4) {
        float4 v0[4], v1[4];
#pragma unroll
        for (int e = 0; e < 4; ++e) {
            const float* xc = xb + (size_t)(cc + e) * N_;
            v0[e] = *(const float4*)(xc + j0);
            v1[e] = *(const float4*)(xc + 2048 + j0);
        }
#pragma unroll
        for (int e = 0; e < 4; ++e) {
            const float* cg = xb + (size_t)(cc + e) * N_ + i0;
            float ce[8];
#pragma unroll
            for (int r = 0; r < RPB; ++r) ce[r] = cg[r];
            float vv[8] = {v0[e].x, v0[e].y, v0[e].z, v0[e].w,
                           v1[e].x, v1[e].y, v1[e].z, v1[e].w};
#pragma unroll
            for (int r = 0; r < RPB; ++r)
#pragma unroll
                for (int q = 0; q < 8; ++q)
                    acc[r][q] = __builtin_fmaf(ce[r], vv[q], acc[r][q]);
        }
    }

    const int wv = tid >> 6, lane = tid & 63;
    float fk[RPB][8];
    {
        float4 s0 = *(const float4*)(sqb + j0);
        float4 s1 = *(const float4*)(sqb + 2048 + j0);
        float sj[8] = {s0.x, s0.y, s0.z, s0.w, s1.x, s1.y, s1.z, s1.w};
#pragma unroll
        for (int r = 0; r < RPB; ++r) {
            float sqi = sqb[i0 + r];
#pragma unroll
            for (int q = 0; q < 8; ++q)
                fk[r][q] = __builtin_fmaf(-2.0f, acc[r][q], sqi) + sj[q];
        }
    }

    float minr[RPB];
#pragma unroll
    for (int r = 0; r < RPB; ++r) {
        float mn = fk[r][0];
#pragma unroll
        for (int q = 1; q < 8; ++q) mn = fminf(mn, fk[r][q]);
        minr[r] = mn;
        mL[r][wv][lane] = mn;
    }
    if (tid < RPB) cntL[tid] = 0;
    __syncthreads();

    {
        float mn = mL[wv][0][lane];
#pragma unroll
        for (int s = 1; s < 8; ++s) mn = fminf(mn, mL[wv][s][lane]);
        float v32 = mn;
#pragma unroll
        for (int k = 2; k <= 64; k <<= 1) {
#pragma unroll
            for (int j = k >> 1; j >= 1; j >>= 1) {
                float pv = __shfl_xor(v32, j);
                bool keepMin = (((lane & j) == 0) == ((lane & k) == 0));
                float lo = v32 < pv ? v32 : pv;
                float hi = v32 < pv ? pv : v32;
                v32 = keepMin ? lo : hi;
            }
        }
        if (lane == 17) tL[wv] = v32;
    }
    __syncthreads();

    {
#pragma unroll
        for (int r = 0; r < RPB; ++r) {
            float Tr = tL[r];
            if (minr[r] <= Tr) {
#pragma unroll
                for (int q = 0; q < 8; ++q) {
                    if (fk[r][q] <= Tr) {
                        int jq = ((q >> 2) << 11) + j0 + (q & 3);
                        u32 s = atomicAdd(&cntL[r], 1u);
                        if (s < 64) bufL[r][s] = ((u64)fkey(fk[r][q]) << 32) | (u32)jq;
                    }
                }
            }
        }
    }
    __syncthreads();

    {
        const int w = wv;
        const u32 cnt = cntL[w];
        const int row = b * N_ + i0 + w;
        if (cnt <= 64) {
            u64 myc = (lane < (int)cnt) ? bufL[w][lane] : ~0ull;
            u32 rank = 0;
            for (u32 m = 0; m < cnt; ++m) {
                u64 o = bufL[w][m];
                rank += (o < myc) ? 1u : 0u;
            }
            if (lane < (int)cnt && rank <= 16 && (rank & 1) == 0)
                out[row * KOUT + (rank >> 1)] = (int)((u32)myc & (N_ - 1));
            if (lane < KOUT)
                out[B_ * N_ * KOUT + row * KOUT + lane] = i0 + w;
        } else {
            const float sqw = sqb[i0 + w];
            u64 L0 = ~0ull, L1 = ~0ull, L2 = ~0ull, L3 = ~0ull, L4 = ~0ull, L5 = ~0ull;
#pragma unroll 1
            for (int m = 0; m < 64; ++m) {
                int j = lane + (m << 6);
                float a = 0.0f;
#pragma unroll 1
                for (int c = 0; c < C_; ++c)
                    a = __builtin_fmaf(cenL[c][w], xb[(size_t)c * N_ + j], a);
                float d = __builtin_fmaf(-2.0f, a, sqw) + sqb[j];
                ins6(((u64)fkey(d) << 32) | (u32)j, L0, L1, L2, L3, L4, L5);
            }
            u64 lastPop = 0;
            u32 myw = 0;
#pragma unroll 1
            for (int r = 0; r < KOUT; ++r) {
                u64 a0 = L0, a1 = L1;
#pragma unroll
                for (int off = 32; off >= 1; off >>= 1) {
                    u64 b0 = __shfl_xor(a0, off);
                    u64 b1 = __shfl_xor(a1, off);
                    u64 lo = (a0 < b0) ? a0 : b0;
                    u64 hi = (a0 < b0) ? b0 : a0;
                    u64 m1 = (a1 < b1) ? a1 : b1;
                    a0 = lo;
                    a1 = (hi < m1) ? hi : m1;
                }
                if (lane == r) myw = (u32)a0;
                bool own0 = ((u32)a0 & 63) == (u32)lane;
                bool own1 = ((u32)a1 & 63) == (u32)lane;
                if (own0) { lastPop = a0; L0 = L1; L1 = L2; L2 = L3; L3 = L4; L4 = L5; L5 = ~0ull; }
                if (own1) { lastPop = a1; L0 = L1; L1 = L2; L2 = L3; L3 = L4; L4 = L5; L5 = ~0ull; }
                if ((own0 || own1) && L1 == ~0ull && r < KOUT - 1) {
                    L0 = L1 = L2 = L3 = L4 = L5 = ~0ull;
#pragma unroll 1
                    for (int m = 0; m < 64; ++m) {
                        int j = lane + (m << 6);
                        float a = 0.0f;
#pragma unroll 1
                        for (int c = 0; c < C_; ++c)
                            a = __builtin_fmaf(cenL[c][w], xb[(size_t)c * N_ + j], a);
                        float d = __builtin_fmaf(-2.0f, a, sqw) + sqb[j];
                        u64 kk = ((u64)fkey(d) << 32) | (u32)j;
                        if (kk > lastPop) ins6(kk, L0, L1, L2, L3, L4, L5);
                    }
                }
            }
            if (lane < KOUT) {
                int o = row * KOUT + lane;
                out[o] = (int)(myw & (N_ - 1));
                out[B_ * N_ * KOUT + o] = i0 + w;
            }
        }
    }
}

// ------- mode-1 prep5: coalesced loads + LDS transpose + coalesced writes -------
// (R11/R14-proven.) 256 thr / 64 points, st[64][33] staging, LINEAR writes.

__global__ __launch_bounds__(256) void prep5_kernel(const float* __restrict__ x,
                                                    float* __restrict__ ws) {
#pragma clang fp contract(off)
    __shared__ float st[64][33];
    const int tid = threadIdx.x;
    const int l = tid & 63;
    const int sub = tid >> 6;
    const int chunk0 = blockIdx.x * 64;
    const int gid = chunk0 + l;
    const int b = gid >> 12, n = gid & (N_ - 1);
    const float* xp = x + (size_t)b * (C_ * N_) + n;

    float v[8];
#pragma unroll
    for (int e = 0; e < 8; ++e) v[e] = xp[(size_t)(8 * sub + e) * N_];
#pragma unroll
    for (int e = 0; e < 8; ++e) st[l][8 * sub + e] = v[e];
    __syncthreads();

    float* xT = ws + XT_OFF_F32 + (size_t)chunk0 * 32;
#pragma unroll
    for (int k = 0; k < 8; ++k) {
        int f = k * 256 + tid;
        xT[f] = st[f >> 5][f & 31];
    }
    u32* xbf = (u32*)ws + XP_OFF_U32 + (size_t)chunk0 * 16;
#pragma unroll
    for (int k = 0; k < 4; ++k) {
        int g = k * 256 + tid;
        int nl = g >> 4, p = g & 15;
        xbf[g] = rne_bf16(st[nl][2 * p]) | (rne_bf16(st[nl][2 * p + 1]) << 16);
    }
    if (sub == 0) {
        float w[C_];
#pragma unroll
        for (int c = 0; c < C_; ++c) { float t = st[l][c]; w[c] = t * t; }
        float r[8];
#pragma unroll
        for (int j = 0; j < 8; ++j) r[j] = w[j];
#pragma unroll
        for (int i = 8; i < 32; i += 8) {
#pragma unroll
            for (int j = 0; j < 8; ++j) r[j] = r[j] + w[i + j];
        }
        ws[gid] = ((r[0] + r[1]) + (r[2] + r[3])) + ((r[4] + r[5]) + (r[6] + r[7]));
    }
}

// ------- mode-1 knn v7: v6 + deeper in-flight loads + shfl-based rank -------
// R17: (1) pass loops unroll 2->4 (4 tile-loads in flight vs 2; pass loops
// are latency-bound per R16's VALU-removal null result). (2) verify rank via
// __shfl broadcast — lane m already holds candidate m's exact key, so
// shfl(myc, m) == bufL[rr][m] bit-exactly; removes ~19 serial dependent LDS
// round-trips per sub-row (~120cy each, un-pipelined) from the critical path.

__global__ __launch_bounds__(TPB3, 2) void knn_kernel_v7(const float* __restrict__ x,
                                                         const float* __restrict__ ws,
                                                         int* __restrict__ out) {
#pragma clang fp contract(off)
    __shared__ float cenL[C_][RPB4];     // 8 KB exact centers (verify + fallback)
    __shared__ float mL[RPB4][64];       // 16 KB per-(row, partition) min upper bound
    __shared__ u64 bufL[RPB4][64];       // 32 KB candidate buffers
    __shared__ u32 cntL[RPB4];
    __shared__ float tL[RPB4];

    const int tid = threadIdx.x;
    const int b = blockIdx.x & 7;               // XCD-batch affinity (proven R2)
    const int i0 = (blockIdx.x >> 3) * RPB4;
    const float* xb = x + (size_t)b * (C_ * N_);
    const float* sqb = ws + b * N_;
    const u32* xbfU = (const u32*)ws + XP_OFF_U32 + (size_t)b * N_ * 16;
    const float* xTb = ws + XT_OFF_F32 + (size_t)b * N_ * 32;

    {   // 2048 center entries, 512 threads, 4 each
#pragma unroll
        for (int k = 0; k < 4; ++k) {
            int t2 = tid + k * 512;
            cenL[t2 >> 6][t2 & 63] = xb[(size_t)(t2 >> 6) * N_ + (i0 + (t2 & 63))];
        }
    }
    if (tid < RPB4) cntL[tid] = 0;
    __syncthreads();

    const int w = tid >> 6, l = tid & 63;
    const int col = l & 15, grp = l >> 4;

    // Four A-frags (row groups h: i0+16h .. i0+16h+15). A/B use identical
    // lane->(n,k) addressing so any within-frag k-relabel cancels (R5-proven).
    short8 af0 = __builtin_bit_cast(short8,
        *(const uint4*)(xbfU + (size_t)(i0 + col) * 16 + grp * 4));
    short8 af1 = __builtin_bit_cast(short8,
        *(const uint4*)(xbfU + (size_t)(i0 + 16 + col) * 16 + grp * 4));
    short8 af2 = __builtin_bit_cast(short8,
        *(const uint4*)(xbfU + (size_t)(i0 + 32 + col) * 16 + grp * 4));
    short8 af3 = __builtin_bit_cast(short8,
        *(const uint4*)(xbfU + (size_t)(i0 + 48 + col) * 16 + grp * 4));
    const f32x4 z4 = {0.0f, 0.0f, 0.0f, 0.0f};

    // index [4h+q] <-> row i0 + 16h + grp*4 + q
    float siU[16], siL[16];
#pragma unroll
    for (int h = 0; h < 4; ++h)
#pragma unroll
        for (int q = 0; q < 4; ++q) {
            float s0 = sqb[i0 + 16 * h + grp * 4 + q];
            siU[4 * h + q] = __builtin_fmaf(SLC2, s0, s0) + SLA2;
            siL[4 * h + q] = __builtin_fmaf(-SLC2, s0, s0) - SLA2;
        }

    const int jw = w << 9;                      // wave's 512-j span base
    const u32* bptr = xbfU + (size_t)(jw + col) * 16 + grp * 4;
    const float* sjp = sqb + jw + col;

    // ---- pass 1: per-(row, partition) minima over ALL 32 tiles (R7 lesson:
    // full pass = proven-tight T). tmin tracks min_t fma(-2,c,sjU_t); siU
    // added after the loop. Partition = (wave, col-pair): 64 disjoint x 64 j.
    float tmin[16];
#pragma unroll
    for (int q = 0; q < 16; ++q) tmin[q] = 3.4e38f;
#pragma unroll 4
    for (int t = 0; t < 32; ++t) {
        uint4 buv = *(const uint4*)(bptr + (size_t)t * 256);
        float sj = sjp[t * 16];
        float sjU = __builtin_fmaf(SLC2, sj, sj);
        short8 bf = __builtin_bit_cast(short8, buv);
        f32x4 c0 = __builtin_amdgcn_mfma_f32_16x16x32_bf16(af0, bf, z4, 0, 0, 0);
        f32x4 c1 = __builtin_amdgcn_mfma_f32_16x16x32_bf16(af1, bf, z4, 0, 0, 0);
        f32x4 c2 = __builtin_amdgcn_mfma_f32_16x16x32_bf16(af2, bf, z4, 0, 0, 0);
        f32x4 c3 = __builtin_amdgcn_mfma_f32_16x16x32_bf16(af3, bf, z4, 0, 0, 0);
#pragma unroll
        for (int q = 0; q < 4; ++q) {
            tmin[q]      = fminf(tmin[q],      __builtin_fmaf(-2.0f, c0[q], sjU));
            tmin[4 + q]  = fminf(tmin[4 + q],  __builtin_fmaf(-2.0f, c1[q], sjU));
            tmin[8 + q]  = fminf(tmin[8 + q],  __builtin_fmaf(-2.0f, c2[q], sjU));
            tmin[12 + q] = fminf(tmin[12 + q], __builtin_fmaf(-2.0f, c3[q], sjU));
        }
    }
#pragma unroll
    for (int q = 0; q < 16; ++q) {
        tmin[q] += siU[q];
        tmin[q] = fminf(tmin[q], __shfl_xor(tmin[q], 1));
    }
    if (!(l & 1)) {
        const int cp = (w << 3) + (col >> 1);
#pragma unroll
        for (int h = 0; h < 4; ++h)
#pragma unroll
            for (int q = 0; q < 4; ++q)
                mL[16 * h + grp * 4 + q][cp] = tmin[4 * h + q];
    }
    __syncthreads();

    // ---- T[row] = 18th-smallest partition min; wave w sorts rows 8w..8w+7
    // (8-way interleaved bitonic; sorted[17] lands in lane 17).
    {
        float v[8];
#pragma unroll
        for (int s = 0; s < 8; ++s) v[s] = mL[8 * w + s][l];
#pragma unroll
        for (int k = 2; k <= 64; k <<= 1) {
#pragma unroll
            for (int j = k >> 1; j >= 1; j >>= 1) {
                bool keepMin = (((l & j) == 0) == ((l & k) == 0));
#pragma unroll
                for (int s = 0; s < 8; ++s) {
                    float pv = __shfl_xor(v[s], j);
                    float lo = v[s] < pv ? v[s] : pv;
                    float hi = v[s] < pv ? pv : v[s];
                    v[s] = keepMin ? lo : hi;
                }
            }
        }
        if (l == 17) {
#pragma unroll
            for (int s = 0; s < 8; ++s) tL[8 * w + s] = v[s];
        }
    }
    __syncthreads();

    // ---- pass 2 (all 32 tiles): admit j if fma(-2,c,sjL) <= TU-siL.
    float TUp[16];
#pragma unroll
    for (int h = 0; h < 4; ++h)
#pragma unroll
        for (int q = 0; q < 4; ++q)
            TUp[4 * h + q] = tL[16 * h + grp * 4 + q] - siL[4 * h + q];
    const int jc = jw + col;
#pragma unroll 4
    for (int t = 0; t < 32; ++t) {
        uint4 buv = *(const uint4*)(bptr + (size_t)t * 256);
        float sj = sjp[t * 16];
        float sjL = __builtin_fmaf(-SLC2, sj, sj);
        short8 bf = __builtin_bit_cast(short8, buv);
        f32x4 c0 = __builtin_amdgcn_mfma_f32_16x16x32_bf16(af0, bf, z4, 0, 0, 0);
        f32x4 c1 = __builtin_amdgcn_mfma_f32_16x16x32_bf16(af1, bf, z4, 0, 0, 0);
        f32x4 c2 = __builtin_amdgcn_mfma_f32_16x16x32_bf16(af2, bf, z4, 0, 0, 0);
        f32x4 c3 = __builtin_amdgcn_mfma_f32_16x16x32_bf16(af3, bf, z4, 0, 0, 0);
        const int jq = jc + (t << 4);
#pragma unroll
        for (int q = 0; q < 4; ++q) {
            float v0 = __builtin_fmaf(-2.0f, c0[q], sjL);
            if (v0 <= TUp[q]) {
                const int rr = grp * 4 + q;
                u32 s = atomicAdd(&cntL[rr], 1u);
                if (s < 64) bufL[rr][s] =
                    ((u64)__float_as_uint(v0 + siL[q]) << 32) | (u32)jq;
            }
            float v1 = __builtin_fmaf(-2.0f, c1[q], sjL);
            if (v1 <= TUp[4 + q]) {
                const int rr = 16 + grp * 4 + q;
                u32 s = atomicAdd(&cntL[rr], 1u);
                if (s < 64) bufL[rr][s] =
                    ((u64)__float_as_uint(v1 + siL[4 + q]) << 32) | (u32)jq;
            }
            float v2 = __builtin_fmaf(-2.0f, c2[q], sjL);
            if (v2 <= TUp[8 + q]) {
                const int rr = 32 + grp * 4 + q;
                u32 s = atomicAdd(&cntL[rr], 1u);
                if (s < 64) bufL[rr][s] =
                    ((u64)__float_as_uint(v2 + siL[8 + q]) << 32) | (u32)jq;
            }
            float v3 = __builtin_fmaf(-2.0f, c3[q], sjL);
            if (v3 <= TUp[12 + q]) {
                const int rr = 48 + grp * 4 + q;
                u32 s = atomicAdd(&cntL[rr], 1u);
                if (s < 64) bufL[rr][s] =
                    ((u64)__float_as_uint(v3 + siL[12 + q]) << 32) | (u32)jq;
            }
        }
    }
    __syncthreads();

    // ---- verify + rank (shfl-based) + band-check; wave w: rows 8w..8w+7.
#pragma unroll 1
    for (int sub = 0; sub < 8; ++sub) {
        const int rr = 8 * w + sub;
        const int row = b * N_ + i0 + rr;
        const u32 cnt = cntL[rr];
        const float sqi = sqb[i0 + rr];
        bool ok = (cnt >= 18u && cnt <= 64u);
        u64 myc = ~0ull;
        bool band = true;
        if (ok && l < (int)cnt) {
            u64 e = bufL[rr][l];
            int jq = (int)(u32)e;
            float lov = __uint_as_float((u32)(e >> 32));
            const float* xj = xTb + (size_t)jq * 32;    // 128 B contiguous
            float a = 0.0f;
#pragma unroll
            for (int c = 0; c < C_; ++c)
                a = __builtin_fmaf(cenL[c][rr], xj[c], a);   // exact chain, c ascending
            float d = __builtin_fmaf(-2.0f, a, sqi) + sqb[jq];
            float sl = __builtin_fmaf(sqi + sqb[jq], SLC2, SLA2);
            float eps = 0.01f + 1e-3f * fabsf(d);
            band = (d + eps >= lov) && (d <= lov + 2.0f * sl + eps);
            myc = ((u64)fkey(d) << 32) | (u32)jq;
        }
        if (__any(!band)) ok = false;           // bounds invalid => exact fallback
        if (ok) {
            // rank via wave broadcast: lane m holds candidate m's exact key,
            // so shfl(myc, m) == old bufL[rr][m] bit-exactly. Dependency-free
            // register crossbar reads pipeline (vs serial LDS round-trips).
            u32 rank = 0;
            for (u32 m = 0; m < cnt; ++m) {
                u64 o = __shfl(myc, (int)m);
                rank += (o < myc) ? 1u : 0u;
            }
            if (l < (int)cnt && rank <= 16 && (rank & 1) == 0)
                out[row * KOUT + (rank >> 1)] = (int)((u32)myc & (N_ - 1));
            if (l < KOUT)
                out[B_ * N_ * KOUT + row * KOUT + l] = i0 + rr;
        } else {
            // exact R7 scan + pop-2 (proven semantics).
            const float sqw = sqi;
            u64 L0 = ~0ull, L1 = ~0ull, L2 = ~0ull, L3 = ~0ull, L4 = ~0ull, L5 = ~0ull;
#pragma unroll 1
            for (int m = 0; m < 64; ++m) {
                int j = l + (m << 6);
                float a = 0.0f;
#pragma unroll
                for (int c = 0; c < C_; ++c)
                    a = __builtin_fmaf(cenL[c][rr], xb[(size_t)c * N_ + j], a);
                float d = __builtin_fmaf(-2.0f, a, sqw) + sqb[j];
                ins6(((u64)fkey(d) << 32) | (u32)j, L0, L1, L2, L3, L4, L5);
            }
            u64 lastPop = 0;
            u32 myw = 0;
#pragma unroll 1
            for (int r = 0; r < KOUT; ++r) {
                u64 a0 = L0, a1 = L1;
#pragma unroll
                for (int off = 32; off >= 1; off >>= 1) {
                    u64 b0 = __shfl_xor(a0, off);
                    u64 b1 = __shfl_xor(a1, off);
                    u64 lo = (a0 < b0) ? a0 : b0;
                    u64 hi = (a0 < b0) ? b0 : a0;
                    u64 m1 = (a1 < b1) ? a1 : b1;
                    a0 = lo;
                    a1 = (hi < m1) ? hi : m1;
                }
                if (l == r) myw = (u32)a0;
                bool own0 = ((u32)a0 & 63) == (u32)l;
                bool own1 = ((u32)a1 & 63) == (u32)l;
                if (own0) { lastPop = a0; L0 = L1; L1 = L2; L2 = L3; L3 = L4; L4 = L5; L5 = ~0ull; }
                if (own1) { lastPop = a1; L0 = L1; L1 = L2; L2 = L3; L3 = L4; L4 = L5; L5 = ~0ull; }
                if ((own0 || own1) && L1 == ~0ull && r < KOUT - 1) {
                    L0 = L1 = L2 = L3 = L4 = L5 = ~0ull;
#pragma unroll 1
                    for (int m = 0; m < 64; ++m) {
                        int j = l + (m << 6);
                        float a = 0.0f;
#pragma unroll
                        for (int c = 0; c < C_; ++c)
                            a = __builtin_fmaf(cenL[c][rr], xb[(size_t)c * N_ + j], a);
                        float d = __builtin_fmaf(-2.0f, a, sqw) + sqb[j];
                        u64 kk = ((u64)fkey(d) << 32) | (u32)j;
                        if (kk > lastPop) ins6(kk, L0, L1, L2, L3, L4, L5);
                    }
                }
            }
            if (l < KOUT) {
                int o = row * KOUT + l;
                out[o] = (int)(myw & (N_ - 1));
                out[B_ * N_ * KOUT + o] = i0 + rr;
            }
        }
    }
}

extern "C" void kernel_launch(void* const* d_in, const int* in_sizes, int n_in,
                              void* d_out, int out_size, void* d_ws, size_t ws_size,
                              hipStream_t stream) {
    const float* x = (const float*)d_in[0];
    float* ws = (float*)d_ws;
    int* out = (int*)d_out;

    if (ws_size >= NEED_XT_B) {
        hipLaunchKernelGGL(prep5_kernel, dim3(B_ * N_ / 64), dim3(256), 0, stream, x, ws);
        hipLaunchKernelGGL(knn_kernel_v7, dim3(B_ * N_ / RPB4), dim3(TPB3), 0, stream,
                           x, ws, out);
    } else {
        hipLaunchKernelGGL(sq_kernel, dim3(B_ * N_ / 256), dim3(256), 0, stream, x, ws);
        hipLaunchKernelGGL(knn_kernel_old, dim3(B_ * N_ / RPB), dim3(TPB), 0, stream,
                           x, ws, out);
    }
}

// Round 18
// 127.225 us; speedup vs baseline: 1.0766x; 1.0766x over previous
//
#include <hip/hip_runtime.h>
#include <stdint.h>

#define B_ 8
#define C_ 32
#define N_ 4096
#define KOUT 9

// mode-0 legacy (tiny workspace) params
#define RPB 8
#define TPB 512

// mode-1 (MFMA prefilter) params
#define RPB4 64     // rows per block; wave w verifies rows 8w..8w+7
#define TPB3 512    // 8 waves; wave w scans j in [512w, 512w+512)

// bf16 bound slack: |d_exact - d_mfma| <= (2u+u^2)*(si+sj), u=2^-8 -> 0.00787
// SLC2 = 1.5x margin; SLA2 covers f32 combine rounding + denormal flush.
// R16 reorder (si hoisted) perturbs bounds ~1e-5 << guaranteed margin.
#define SLC2 0.012f
#define SLA2 0.004f

// ws layout (float units): [sq: B*N][xbf u32: B*N*16][xT f32: B*N*32]
// xT (R12 lesson): contiguous 128B gather = 2 cache lines/candidate.
#define SQ_FLOATS   (B_ * N_)
#define XP_OFF_U32  (SQ_FLOATS)
#define XT_OFF_F32  (SQ_FLOATS + B_ * 16 * N_)
#define NEED_XT_B   ((size_t)(XT_OFF_F32 + B_ * N_ * C_) * 4)   // 6,422,528

typedef unsigned long long u64;
typedef unsigned int u32;
typedef __attribute__((ext_vector_type(8))) short short8;   // 8 bf16 (4 VGPRs)
typedef __attribute__((ext_vector_type(4))) float f32x4;

// monotone float->uint mapping: a<b <=> fkey(a)<fkey(b) (exact keys only)
__device__ __forceinline__ u32 fkey(float f) {
    u32 u = __float_as_uint(f);
    return u ^ (u32)((((int)u) >> 31) | 0x80000000u);
}

// f32 -> bf16 RNE (no NaN/Inf in data)
__device__ __forceinline__ u32 rne_bf16(float f) {
    u32 u = __float_as_uint(f);
    return (u + 0x7fffu + ((u >> 16) & 1u)) >> 16;
}

// branchless insert keep-6-smallest — exact fallback only
__device__ __forceinline__ void ins6(u64 k, u64& L0, u64& L1, u64& L2,
                                     u64& L3, u64& L4, u64& L5) {
    bool lt0 = k < L0, lt1 = k < L1, lt2 = k < L2,
         lt3 = k < L3, lt4 = k < L4, lt5 = k < L5;
    L5 = lt4 ? L4 : (lt5 ? k : L5);
    L4 = lt3 ? L3 : (lt4 ? k : L4);
    L3 = lt2 ? L2 : (lt3 ? k : L3);
    L2 = lt1 ? L1 : (lt2 ? k : L2);
    L1 = lt0 ? L0 : (lt1 ? k : L1);
    L0 = lt0 ? k : L0;
}

// ---------------- mode-0: proven R13 pipeline (unchanged) ----------------

__global__ __launch_bounds__(256) void sq_kernel(const float* __restrict__ x,
                                                 float* __restrict__ sq) {
#pragma clang fp contract(off)
    int gid = blockIdx.x * 256 + threadIdx.x;
    int b = gid >> 12, n = gid & (N_ - 1);
    const float* xp = x + (size_t)b * (C_ * N_) + n;
    float w[C_];
#pragma unroll
    for (int c = 0; c < C_; ++c) { float v = xp[(size_t)c * N_]; w[c] = v * v; }
    float r[8];
#pragma unroll
    for (int j = 0; j < 8; ++j) r[j] = w[j];
#pragma unroll
    for (int i = 8; i < 32; i += 8) {
#pragma unroll
        for (int j = 0; j < 8; ++j) r[j] = r[j] + w[i + j];
    }
    sq[gid] = ((r[0] + r[1]) + (r[2] + r[3])) + ((r[4] + r[5]) + (r[6] + r[7]));
}

__global__ __launch_bounds__(TPB, 4) void knn_kernel_old(const float* __restrict__ x,
                                                         const float* __restrict__ sq,
                                                         int* __restrict__ out) {
#pragma clang fp contract(off)
    __shared__ float cenL[C_][RPB];
    __shared__ float mL[RPB][8][64];
    __shared__ u64 bufL[RPB][64];
    __shared__ u32 cntL[RPB];
    __shared__ float tL[RPB];

    const int tid = threadIdx.x;
    const int b = blockIdx.x & 7;
    const int i0 = (blockIdx.x >> 3) * RPB;
    const float* xb = x + (size_t)b * (C_ * N_);
    const float* sqb = sq + b * N_;

    if (tid < RPB * C_) {
        int r = tid & (RPB - 1), c = tid >> 3;
        cenL[c][r] = xb[(size_t)c * N_ + (i0 + r)];
    }
    __syncthreads();

    float acc[RPB][8];
#pragma unroll
    for (int r = 0; r < RPB; ++r)
#pragma unroll
        for (int q = 0; q < 8; ++q) acc[r][q] = 0.0f;

    const int j0 = tid << 2;
#pragma unroll 1
    for (int cc = 0; cc < C_; cc += 4) {
        float4 v0[4], v1[4];
#pragma unroll
        for (int e = 0; e < 4; ++e) {
            const float* xc = xb + (size_t)(cc + e) * N_;
            v0[e] = *(const float4*)(xc + j0);
            v1[e] = *(const float4*)(xc + 2048 + j0);
        }
#pragma unroll
        for (int e = 0; e < 4; ++e) {
            const float* cg = xb + (size_t)(cc + e) * N_ + i0;
            float ce[8];
#pragma unroll
            for (int r = 0; r < RPB; ++r) ce[r] = cg[r];
            float vv[8] = {v0[e].x, v0[e].y, v0[e].z, v0[e].w,
                           v1[e].x, v1[e].y, v1[e].z, v1[e].w};
#pragma unroll
            for (int r = 0; r < RPB; ++r)
#pragma unroll
                for (int q = 0; q < 8; ++q)
                    acc[r][q] = __builtin_fmaf(ce[r], vv[q], acc[r][q]);
        }
    }

    const int wv = tid >> 6, lane = tid & 63;
    float fk[RPB][8];
    {
        float4 s0 = *(const float4*)(sqb + j0);
        float4 s1 = *(const float4*)(sqb + 2048 + j0);
        float sj[8] = {s0.x, s0.y, s0.z, s0.w, s1.x, s1.y, s1.z, s1.w};
#pragma unroll
        for (int r = 0; r < RPB; ++r) {
            float sqi = sqb[i0 + r];
#pragma unroll
            for (int q = 0; q < 8; ++q)
                fk[r][q] = __builtin_fmaf(-2.0f, acc[r][q], sqi) + sj[q];
        }
    }

    float minr[RPB];
#pragma unroll
    for (int r = 0; r < RPB; ++r) {
        float mn = fk[r][0];
#pragma unroll
        for (int q = 1; q < 8; ++q) mn = fminf(mn, fk[r][q]);
        minr[r] = mn;
        mL[r][wv][lane] = mn;
    }
    if (tid < RPB) cntL[tid] = 0;
    __syncthreads();

    {
        float mn = mL[wv][0][lane];
#pragma unroll
        for (int s = 1; s < 8; ++s) mn = fminf(mn, mL[wv][s][lane]);
        float v32 = mn;
#pragma unroll
        for (int k = 2; k <= 64; k <<= 1) {
#pragma unroll
            for (int j = k >> 1; j >= 1; j >>= 1) {
                float pv = __shfl_xor(v32, j);
                bool keepMin = (((lane & j) == 0) == ((lane & k) == 0));
                float lo = v32 < pv ? v32 : pv;
                float hi = v32 < pv ? pv : v32;
                v32 = keepMin ? lo : hi;
            }
        }
        if (lane == 17) tL[wv] = v32;
    }
    __syncthreads();

    {
#pragma unroll
        for (int r = 0; r < RPB; ++r) {
            float Tr = tL[r];
            if (minr[r] <= Tr) {
#pragma unroll
                for (int q = 0; q < 8; ++q) {
                    if (fk[r][q] <= Tr) {
                        int jq = ((q >> 2) << 11) + j0 + (q & 3);
                        u32 s = atomicAdd(&cntL[r], 1u);
                        if (s < 64) bufL[r][s] = ((u64)fkey(fk[r][q]) << 32) | (u32)jq;
                    }
                }
            }
        }
    }
    __syncthreads();

    {
        const int w = wv;
        const u32 cnt = cntL[w];
        const int row = b * N_ + i0 + w;
        if (cnt <= 64) {
            u64 myc = (lane < (int)cnt) ? bufL[w][lane] : ~0ull;
            u32 rank = 0;
            for (u32 m = 0; m < cnt; ++m) {
                u64 o = bufL[w][m];
                rank += (o < myc) ? 1u : 0u;
            }
            if (lane < (int)cnt && rank <= 16 && (rank & 1) == 0)
                out[row * KOUT + (rank >> 1)] = (int)((u32)myc & (N_ - 1));
            if (lane < KOUT)
                out[B_ * N_ * KOUT + row * KOUT + lane] = i0 + w;
        } else {
            const float sqw = sqb[i0 + w];
            u64 L0 = ~0ull, L1 = ~0ull, L2 = ~0ull, L3 = ~0ull, L4 = ~0ull, L5 = ~0ull;
#pragma unroll 1
            for (int m = 0; m < 64; ++m) {
                int j = lane + (m << 6);
                float a = 0.0f;
#pragma unroll 1
                for (int c = 0; c < C_; ++c)
                    a = __builtin_fmaf(cenL[c][w], xb[(size_t)c * N_ + j], a);
                float d = __builtin_fmaf(-2.0f, a, sqw) + sqb[j];
                ins6(((u64)fkey(d) << 32) | (u32)j, L0, L1, L2, L3, L4, L5);
            }
            u64 lastPop = 0;
            u32 myw = 0;
#pragma unroll 1
            for (int r = 0; r < KOUT; ++r) {
                u64 a0 = L0, a1 = L1;
#pragma unroll
                for (int off = 32; off >= 1; off >>= 1) {
                    u64 b0 = __shfl_xor(a0, off);
                    u64 b1 = __shfl_xor(a1, off);
                    u64 lo = (a0 < b0) ? a0 : b0;
                    u64 hi = (a0 < b0) ? b0 : a0;
                    u64 m1 = (a1 < b1) ? a1 : b1;
                    a0 = lo;
                    a1 = (hi < m1) ? hi : m1;
                }
                if (lane == r) myw = (u32)a0;
                bool own0 = ((u32)a0 & 63) == (u32)lane;
                bool own1 = ((u32)a1 & 63) == (u32)lane;
                if (own0) { lastPop = a0; L0 = L1; L1 = L2; L2 = L3; L3 = L4; L4 = L5; L5 = ~0ull; }
                if (own1) { lastPop = a1; L0 = L1; L1 = L2; L2 = L3; L3 = L4; L4 = L5; L5 = ~0ull; }
                if ((own0 || own1) && L1 == ~0ull && r < KOUT - 1) {
                    L0 = L1 = L2 = L3 = L4 = L5 = ~0ull;
#pragma unroll 1
                    for (int m = 0; m < 64; ++m) {
                        int j = lane + (m << 6);
                        float a = 0.0f;
#pragma unroll 1
                        for (int c = 0; c < C_; ++c)
                            a = __builtin_fmaf(cenL[c][w], xb[(size_t)c * N_ + j], a);
                        float d = __builtin_fmaf(-2.0f, a, sqw) + sqb[j];
                        u64 kk = ((u64)fkey(d) << 32) | (u32)j;
                        if (kk > lastPop) ins6(kk, L0, L1, L2, L3, L4, L5);
                    }
                }
            }
            if (lane < KOUT) {
                int o = row * KOUT + lane;
                out[o] = (int)(myw & (N_ - 1));
                out[B_ * N_ * KOUT + o] = i0 + w;
            }
        }
    }
}

// ------- mode-1 prep5: coalesced loads + LDS transpose + coalesced writes -------
// (R11/R14/R16-proven.) 256 thr / 64 points, st[64][33] staging, LINEAR writes.

__global__ __launch_bounds__(256) void prep5_kernel(const float* __restrict__ x,
                                                    float* __restrict__ ws) {
#pragma clang fp contract(off)
    __shared__ float st[64][33];
    const int tid = threadIdx.x;
    const int l = tid & 63;
    const int sub = tid >> 6;
    const int chunk0 = blockIdx.x * 64;
    const int gid = chunk0 + l;
    const int b = gid >> 12, n = gid & (N_ - 1);
    const float* xp = x + (size_t)b * (C_ * N_) + n;

    float v[8];
#pragma unroll
    for (int e = 0; e < 8; ++e) v[e] = xp[(size_t)(8 * sub + e) * N_];
#pragma unroll
    for (int e = 0; e < 8; ++e) st[l][8 * sub + e] = v[e];
    __syncthreads();

    float* xT = ws + XT_OFF_F32 + (size_t)chunk0 * 32;
#pragma unroll
    for (int k = 0; k < 8; ++k) {
        int f = k * 256 + tid;
        xT[f] = st[f >> 5][f & 31];
    }
    u32* xbf = (u32*)ws + XP_OFF_U32 + (size_t)chunk0 * 16;
#pragma unroll
    for (int k = 0; k < 4; ++k) {
        int g = k * 256 + tid;
        int nl = g >> 4, p = g & 15;
        xbf[g] = rne_bf16(st[nl][2 * p]) | (rne_bf16(st[nl][2 * p + 1]) << 16);
    }
    if (sub == 0) {
        float w[C_];
#pragma unroll
        for (int c = 0; c < C_; ++c) { float t = st[l][c]; w[c] = t * t; }
        float r[8];
#pragma unroll
        for (int j = 0; j < 8; ++j) r[j] = w[j];
#pragma unroll
        for (int i = 8; i < 32; i += 8) {
#pragma unroll
            for (int j = 0; j < 8; ++j) r[j] = r[j] + w[i + j];
        }
        ws[gid] = ((r[0] + r[1]) + (r[2] + r[3])) + ((r[4] + r[5]) + (r[6] + r[7]));
    }
}

// ------- mode-1 knn v6 (R16-proven best, 77.8us): 64-row blocks, 4 MFMA ------
// per B-load, si hoisted out of pass loops, unroll 2, LDS-broadcast rank.
// R17 lesson: dynamic-index __shfl = ds_bpermute (LDS hardware, 2x for u64)
// — NOT cheaper than broadcast ds_read; induction-addressed load loops
// already pipeline. unroll 4 perturbs proven scheduling (R11 precedent).

__global__ __launch_bounds__(TPB3, 2) void knn_kernel_v6(const float* __restrict__ x,
                                                         const float* __restrict__ ws,
                                                         int* __restrict__ out) {
#pragma clang fp contract(off)
    __shared__ float cenL[C_][RPB4];     // 8 KB exact centers (verify + fallback)
    __shared__ float mL[RPB4][64];       // 16 KB per-(row, partition) min upper bound
    __shared__ u64 bufL[RPB4][64];       // 32 KB candidate buffers
    __shared__ u32 cntL[RPB4];
    __shared__ float tL[RPB4];

    const int tid = threadIdx.x;
    const int b = blockIdx.x & 7;               // XCD-batch affinity (proven R2)
    const int i0 = (blockIdx.x >> 3) * RPB4;
    const float* xb = x + (size_t)b * (C_ * N_);
    const float* sqb = ws + b * N_;
    const u32* xbfU = (const u32*)ws + XP_OFF_U32 + (size_t)b * N_ * 16;
    const float* xTb = ws + XT_OFF_F32 + (size_t)b * N_ * 32;

    {   // 2048 center entries, 512 threads, 4 each
#pragma unroll
        for (int k = 0; k < 4; ++k) {
            int t2 = tid + k * 512;
            cenL[t2 >> 6][t2 & 63] = xb[(size_t)(t2 >> 6) * N_ + (i0 + (t2 & 63))];
        }
    }
    if (tid < RPB4) cntL[tid] = 0;
    __syncthreads();

    const int w = tid >> 6, l = tid & 63;
    const int col = l & 15, grp = l >> 4;

    // Four A-frags (row groups h: i0+16h .. i0+16h+15). A/B use identical
    // lane->(n,k) addressing so any within-frag k-relabel cancels (R5-proven).
    short8 af0 = __builtin_bit_cast(short8,
        *(const uint4*)(xbfU + (size_t)(i0 + col) * 16 + grp * 4));
    short8 af1 = __builtin_bit_cast(short8,
        *(const uint4*)(xbfU + (size_t)(i0 + 16 + col) * 16 + grp * 4));
    short8 af2 = __builtin_bit_cast(short8,
        *(const uint4*)(xbfU + (size_t)(i0 + 32 + col) * 16 + grp * 4));
    short8 af3 = __builtin_bit_cast(short8,
        *(const uint4*)(xbfU + (size_t)(i0 + 48 + col) * 16 + grp * 4));
    const f32x4 z4 = {0.0f, 0.0f, 0.0f, 0.0f};

    // index [4h+q] <-> row i0 + 16h + grp*4 + q
    float siU[16], siL[16];
#pragma unroll
    for (int h = 0; h < 4; ++h)
#pragma unroll
        for (int q = 0; q < 4; ++q) {
            float s0 = sqb[i0 + 16 * h + grp * 4 + q];
            siU[4 * h + q] = __builtin_fmaf(SLC2, s0, s0) + SLA2;
            siL[4 * h + q] = __builtin_fmaf(-SLC2, s0, s0) - SLA2;
        }

    const int jw = w << 9;                      // wave's 512-j span base
    const u32* bptr = xbfU + (size_t)(jw + col) * 16 + grp * 4;
    const float* sjp = sqb + jw + col;

    // ---- pass 1: per-(row, partition) minima over ALL 32 tiles (R7 lesson:
    // full pass = proven-tight T). tmin tracks min_t fma(-2,c,sjU_t); siU
    // added after the loop. Partition = (wave, col-pair): 64 disjoint x 64 j.
    float tmin[16];
#pragma unroll
    for (int q = 0; q < 16; ++q) tmin[q] = 3.4e38f;
#pragma unroll 2
    for (int t = 0; t < 32; ++t) {
        uint4 buv = *(const uint4*)(bptr + (size_t)t * 256);
        float sj = sjp[t * 16];
        float sjU = __builtin_fmaf(SLC2, sj, sj);
        short8 bf = __builtin_bit_cast(short8, buv);
        f32x4 c0 = __builtin_amdgcn_mfma_f32_16x16x32_bf16(af0, bf, z4, 0, 0, 0);
        f32x4 c1 = __builtin_amdgcn_mfma_f32_16x16x32_bf16(af1, bf, z4, 0, 0, 0);
        f32x4 c2 = __builtin_amdgcn_mfma_f32_16x16x32_bf16(af2, bf, z4, 0, 0, 0);
        f32x4 c3 = __builtin_amdgcn_mfma_f32_16x16x32_bf16(af3, bf, z4, 0, 0, 0);
#pragma unroll
        for (int q = 0; q < 4; ++q) {
            tmin[q]      = fminf(tmin[q],      __builtin_fmaf(-2.0f, c0[q], sjU));
            tmin[4 + q]  = fminf(tmin[4 + q],  __builtin_fmaf(-2.0f, c1[q], sjU));
            tmin[8 + q]  = fminf(tmin[8 + q],  __builtin_fmaf(-2.0f, c2[q], sjU));
            tmin[12 + q] = fminf(tmin[12 + q], __builtin_fmaf(-2.0f, c3[q], sjU));
        }
    }
#pragma unroll
    for (int q = 0; q < 16; ++q) {
        tmin[q] += siU[q];
        tmin[q] = fminf(tmin[q], __shfl_xor(tmin[q], 1));
    }
    if (!(l & 1)) {
        const int cp = (w << 3) + (col >> 1);
#pragma unroll
        for (int h = 0; h < 4; ++h)
#pragma unroll
            for (int q = 0; q < 4; ++q)
                mL[16 * h + grp * 4 + q][cp] = tmin[4 * h + q];
    }
    __syncthreads();

    // ---- T[row] = 18th-smallest partition min; wave w sorts rows 8w..8w+7
    // (8-way interleaved bitonic; sorted[17] lands in lane 17).
    {
        float v[8];
#pragma unroll
        for (int s = 0; s < 8; ++s) v[s] = mL[8 * w + s][l];
#pragma unroll
        for (int k = 2; k <= 64; k <<= 1) {
#pragma unroll
            for (int j = k >> 1; j >= 1; j >>= 1) {
                bool keepMin = (((l & j) == 0) == ((l & k) == 0));
#pragma unroll
                for (int s = 0; s < 8; ++s) {
                    float pv = __shfl_xor(v[s], j);
                    float lo = v[s] < pv ? v[s] : pv;
                    float hi = v[s] < pv ? pv : v[s];
                    v[s] = keepMin ? lo : hi;
                }
            }
        }
        if (l == 17) {
#pragma unroll
            for (int s = 0; s < 8; ++s) tL[8 * w + s] = v[s];
        }
    }
    __syncthreads();

    // ---- pass 2 (all 32 tiles): admit j if fma(-2,c,sjL) <= TU-siL.
    float TUp[16];
#pragma unroll
    for (int h = 0; h < 4; ++h)
#pragma unroll
        for (int q = 0; q < 4; ++q)
            TUp[4 * h + q] = tL[16 * h + grp * 4 + q] - siL[4 * h + q];
    const int jc = jw + col;
#pragma unroll 2
    for (int t = 0; t < 32; ++t) {
        uint4 buv = *(const uint4*)(bptr + (size_t)t * 256);
        float sj = sjp[t * 16];
        float sjL = __builtin_fmaf(-SLC2, sj, sj);
        short8 bf = __builtin_bit_cast(short8, buv);
        f32x4 c0 = __builtin_amdgcn_mfma_f32_16x16x32_bf16(af0, bf, z4, 0, 0, 0);
        f32x4 c1 = __builtin_amdgcn_mfma_f32_16x16x32_bf16(af1, bf, z4, 0, 0, 0);
        f32x4 c2 = __builtin_amdgcn_mfma_f32_16x16x32_bf16(af2, bf, z4, 0, 0, 0);
        f32x4 c3 = __builtin_amdgcn_mfma_f32_16x16x32_bf16(af3, bf, z4, 0, 0, 0);
        const int jq = jc + (t << 4);
#pragma unroll
        for (int q = 0; q < 4; ++q) {
            float v0 = __builtin_fmaf(-2.0f, c0[q], sjL);
            if (v0 <= TUp[q]) {
                const int rr = grp * 4 + q;
                u32 s = atomicAdd(&cntL[rr], 1u);
                if (s < 64) bufL[rr][s] =
                    ((u64)__float_as_uint(v0 + siL[q]) << 32) | (u32)jq;
            }
            float v1 = __builtin_fmaf(-2.0f, c1[q], sjL);
            if (v1 <= TUp[4 + q]) {
                const int rr = 16 + grp * 4 + q;
                u32 s = atomicAdd(&cntL[rr], 1u);
                if (s < 64) bufL[rr][s] =
                    ((u64)__float_as_uint(v1 + siL[4 + q]) << 32) | (u32)jq;
            }
            float v2 = __builtin_fmaf(-2.0f, c2[q], sjL);
            if (v2 <= TUp[8 + q]) {
                const int rr = 32 + grp * 4 + q;
                u32 s = atomicAdd(&cntL[rr], 1u);
                if (s < 64) bufL[rr][s] =
                    ((u64)__float_as_uint(v2 + siL[8 + q]) << 32) | (u32)jq;
            }
            float v3 = __builtin_fmaf(-2.0f, c3[q], sjL);
            if (v3 <= TUp[12 + q]) {
                const int rr = 48 + grp * 4 + q;
                u32 s = atomicAdd(&cntL[rr], 1u);
                if (s < 64) bufL[rr][s] =
                    ((u64)__float_as_uint(v3 + siL[12 + q]) << 32) | (u32)jq;
            }
        }
    }
    __syncthreads();

    // ---- verify + rank (proven) + band-check; wave w: rows 8w..8w+7.
#pragma unroll 1
    for (int sub = 0; sub < 8; ++sub) {
        const int rr = 8 * w + sub;
        const int row = b * N_ + i0 + rr;
        const u32 cnt = cntL[rr];
        const float sqi = sqb[i0 + rr];
        bool ok = (cnt >= 18u && cnt <= 64u);
        u64 myc = ~0ull;
        bool band = true;
        if (ok && l < (int)cnt) {
            u64 e = bufL[rr][l];
            int jq = (int)(u32)e;
            float lov = __uint_as_float((u32)(e >> 32));
            const float* xj = xTb + (size_t)jq * 32;    // 128 B contiguous
            float a = 0.0f;
#pragma unroll
            for (int c = 0; c < C_; ++c)
                a = __builtin_fmaf(cenL[c][rr], xj[c], a);   // exact chain, c ascending
            float d = __builtin_fmaf(-2.0f, a, sqi) + sqb[jq];
            float sl = __builtin_fmaf(sqi + sqb[jq], SLC2, SLA2);
            float eps = 0.01f + 1e-3f * fabsf(d);
            band = (d + eps >= lov) && (d <= lov + 2.0f * sl + eps);
            myc = ((u64)fkey(d) << 32) | (u32)jq;
        }
        if (__any(!band)) ok = false;           // bounds invalid => exact fallback
        if (ok) {
            if (l < (int)cnt) bufL[rr][l] = myc;     // same-wave LDS, in-order
            u32 rank = 0;
            for (u32 m = 0; m < cnt; ++m) {
                u64 o = bufL[rr][m];                 // broadcast read
                rank += (o < myc) ? 1u : 0u;
            }
            if (l < (int)cnt && rank <= 16 && (rank & 1) == 0)
                out[row * KOUT + (rank >> 1)] = (int)((u32)myc & (N_ - 1));
            if (l < KOUT)
                out[B_ * N_ * KOUT + row * KOUT + l] = i0 + rr;
        } else {
            // exact R7 scan + pop-2 (proven semantics).
            const float sqw = sqi;
            u64 L0 = ~0ull, L1 = ~0ull, L2 = ~0ull, L3 = ~0ull, L4 = ~0ull, L5 = ~0ull;
#pragma unroll 1
            for (int m = 0; m < 64; ++m) {
                int j = l + (m << 6);
                float a = 0.0f;
#pragma unroll
                for (int c = 0; c < C_; ++c)
                    a = __builtin_fmaf(cenL[c][rr], xb[(size_t)c * N_ + j], a);
                float d = __builtin_fmaf(-2.0f, a, sqw) + sqb[j];
                ins6(((u64)fkey(d) << 32) | (u32)j, L0, L1, L2, L3, L4, L5);
            }
            u64 lastPop = 0;
            u32 myw = 0;
#pragma unroll 1
            for (int r = 0; r < KOUT; ++r) {
                u64 a0 = L0, a1 = L1;
#pragma unroll
                for (int off = 32; off >= 1; off >>= 1) {
                    u64 b0 = __shfl_xor(a0, off);
                    u64 b1 = __shfl_xor(a1, off);
                    u64 lo = (a0 < b0) ? a0 : b0;
                    u64 hi = (a0 < b0) ? b0 : a0;
                    u64 m1 = (a1 < b1) ? a1 : b1;
                    a0 = lo;
                    a1 = (hi < m1) ? hi : m1;
                }
                if (l == r) myw = (u32)a0;
                bool own0 = ((u32)a0 & 63) == (u32)l;
                bool own1 = ((u32)a1 & 63) == (u32)l;
                if (own0) { lastPop = a0; L0 = L1; L1 = L2; L2 = L3; L3 = L4; L4 = L5; L5 = ~0ull; }
                if (own1) { lastPop = a1; L0 = L1; L1 = L2; L2 = L3; L3 = L4; L4 = L5; L5 = ~0ull; }
                if ((own0 || own1) && L1 == ~0ull && r < KOUT - 1) {
                    L0 = L1 = L2 = L3 = L4 = L5 = ~0ull;
#pragma unroll 1
                    for (int m = 0; m < 64; ++m) {
                        int j = l + (m << 6);
                        float a = 0.0f;
#pragma unroll
                        for (int c = 0; c < C_; ++c)
                            a = __builtin_fmaf(cenL[c][rr], xb[(size_t)c * N_ + j], a);
                        float d = __builtin_fmaf(-2.0f, a, sqw) + sqb[j];
                        u64 kk = ((u64)fkey(d) << 32) | (u32)j;
                        if (kk > lastPop) ins6(kk, L0, L1, L2, L3, L4, L5);
                    }
                }
            }
            if (l < KOUT) {
                int o = row * KOUT + l;
                out[o] = (int)(myw & (N_ - 1));
                out[B_ * N_ * KOUT + o] = i0 + rr;
            }
        }
    }
}

extern "C" void kernel_launch(void* const* d_in, const int* in_sizes, int n_in,
                              void* d_out, int out_size, void* d_ws, size_t ws_size,
                              hipStream_t stream) {
    const float* x = (const float*)d_in[0];
    float* ws = (float*)d_ws;
    int* out = (int*)d_out;

    if (ws_size >= NEED_XT_B) {
        hipLaunchKernelGGL(prep5_kernel, dim3(B_ * N_ / 64), dim3(256), 0, stream, x, ws);
        hipLaunchKernelGGL(knn_kernel_v6, dim3(B_ * N_ / RPB4), dim3(TPB3), 0, stream,
                           x, ws, out);
    } else {
        hipLaunchKernelGGL(sq_kernel, dim3(B_ * N_ / 256), dim3(256), 0, stream, x, ws);
        hipLaunchKernelGGL(knn_kernel_old, dim3(B_ * N_ / RPB), dim3(TPB), 0, stream,
                           x, ws, out);
    }
}

// Round 20
// 126.415 us; speedup vs baseline: 1.0835x; 1.0064x over previous
//
#include <hip/hip_runtime.h>
#include <stdint.h>

#define B_ 8
#define C_ 32
#define N_ 4096
#define KOUT 9

// mode-0 legacy (tiny workspace) params
#define RPB 8
#define TPB 512

// mode-1 (MFMA prefilter) params
#define RPB4 64     // rows per block; wave w verifies rows 8w..8w+7
#define TPB3 512    // 8 waves; wave w scans j in [512w, 512w+512)

// bf16 bound slack: |d_exact - d_mfma| <= (2u+u^2)*(si+sj), u=2^-8 -> 0.00787
// SLC2 = 1.5x margin; SLA2 covers f32 combine rounding + denormal flush.
// R16 reorder (si hoisted) perturbs bounds ~1e-5 << guaranteed margin.
#define SLC2 0.012f
#define SLA2 0.004f

// ws layout (float units): [sq: B*N][xbf u32: B*N*16][xT f32: B*N*32]
// xT (R12 lesson): contiguous 128B gather = 2 cache lines/candidate.
#define SQ_FLOATS   (B_ * N_)
#define XP_OFF_U32  (SQ_FLOATS)
#define XT_OFF_F32  (SQ_FLOATS + B_ * 16 * N_)
#define NEED_XT_B   ((size_t)(XT_OFF_F32 + B_ * N_ * C_) * 4)   // 6,422,528

typedef unsigned long long u64;
typedef unsigned int u32;
typedef __attribute__((ext_vector_type(8))) short short8;   // 8 bf16 (4 VGPRs)
typedef __attribute__((ext_vector_type(4))) float f32x4;

// monotone float->uint mapping: a<b <=> fkey(a)<fkey(b) (exact keys only)
__device__ __forceinline__ u32 fkey(float f) {
    u32 u = __float_as_uint(f);
    return u ^ (u32)((((int)u) >> 31) | 0x80000000u);
}

// f32 -> bf16 RNE (no NaN/Inf in data)
__device__ __forceinline__ u32 rne_bf16(float f) {
    u32 u = __float_as_uint(f);
    return (u + 0x7fffu + ((u >> 16) & 1u)) >> 16;
}

// branchless insert keep-6-smallest — exact fallback only
__device__ __forceinline__ void ins6(u64 k, u64& L0, u64& L1, u64& L2,
                                     u64& L3, u64& L4, u64& L5) {
    bool lt0 = k < L0, lt1 = k < L1, lt2 = k < L2,
         lt3 = k < L3, lt4 = k < L4, lt5 = k < L5;
    L5 = lt4 ? L4 : (lt5 ? k : L5);
    L4 = lt3 ? L3 : (lt4 ? k : L4);
    L3 = lt2 ? L2 : (lt3 ? k : L3);
    L2 = lt1 ? L1 : (lt2 ? k : L2);
    L1 = lt0 ? L0 : (lt1 ? k : L1);
    L0 = lt0 ? k : L0;
}

// ---------------- mode-0: proven R13 pipeline (unchanged) ----------------

__global__ __launch_bounds__(256) void sq_kernel(const float* __restrict__ x,
                                                 float* __restrict__ sq) {
#pragma clang fp contract(off)
    int gid = blockIdx.x * 256 + threadIdx.x;
    int b = gid >> 12, n = gid & (N_ - 1);
    const float* xp = x + (size_t)b * (C_ * N_) + n;
    float w[C_];
#pragma unroll
    for (int c = 0; c < C_; ++c) { float v = xp[(size_t)c * N_]; w[c] = v * v; }
    float r[8];
#pragma unroll
    for (int j = 0; j < 8; ++j) r[j] = w[j];
#pragma unroll
    for (int i = 8; i < 32; i += 8) {
#pragma unroll
        for (int j = 0; j < 8; ++j) r[j] = r[j] + w[i + j];
    }
    sq[gid] = ((r[0] + r[1]) + (r[2] + r[3])) + ((r[4] + r[5]) + (r[6] + r[7]));
}

__global__ __launch_bounds__(TPB, 4) void knn_kernel_old(const float* __restrict__ x,
                                                         const float* __restrict__ sq,
                                                         int* __restrict__ out) {
#pragma clang fp contract(off)
    __shared__ float cenL[C_][RPB];
    __shared__ float mL[RPB][8][64];
    __shared__ u64 bufL[RPB][64];
    __shared__ u32 cntL[RPB];
    __shared__ float tL[RPB];

    const int tid = threadIdx.x;
    const int b = blockIdx.x & 7;
    const int i0 = (blockIdx.x >> 3) * RPB;
    const float* xb = x + (size_t)b * (C_ * N_);
    const float* sqb = sq + b * N_;

    if (tid < RPB * C_) {
        int r = tid & (RPB - 1), c = tid >> 3;
        cenL[c][r] = xb[(size_t)c * N_ + (i0 + r)];
    }
    __syncthreads();

    float acc[RPB][8];
#pragma unroll
    for (int r = 0; r < RPB; ++r)
#pragma unroll
        for (int q = 0; q < 8; ++q) acc[r][q] = 0.0f;

    const int j0 = tid << 2;
#pragma unroll 1
    for (int cc = 0; cc < C_; cc += 4) {
        float4 v0[4], v1[4];
#pragma unroll
        for (int e = 0; e < 4; ++e) {
            const float* xc = xb + (size_t)(cc + e) * N_;
            v0[e] = *(const float4*)(xc + j0);
            v1[e] = *(const float4*)(xc + 2048 + j0);
        }
#pragma unroll
        for (int e = 0; e < 4; ++e) {
            const float* cg = xb + (size_t)(cc + e) * N_ + i0;
            float ce[8];
#pragma unroll
            for (int r = 0; r < RPB; ++r) ce[r] = cg[r];
            float vv[8] = {v0[e].x, v0[e].y, v0[e].z, v0[e].w,
                           v1[e].x, v1[e].y, v1[e].z, v1[e].w};
#pragma unroll
            for (int r = 0; r < RPB; ++r)
#pragma unroll
                for (int q = 0; q < 8; ++q)
                    acc[r][q] = __builtin_fmaf(ce[r], vv[q], acc[r][q]);
        }
    }

    const int wv = tid >> 6, lane = tid & 63;
    float fk[RPB][8];
    {
        float4 s0 = *(const float4*)(sqb + j0);
        float4 s1 = *(const float4*)(sqb + 2048 + j0);
        float sj[8] = {s0.x, s0.y, s0.z, s0.w, s1.x, s1.y, s1.z, s1.w};
#pragma unroll
        for (int r = 0; r < RPB; ++r) {
            float sqi = sqb[i0 + r];
#pragma unroll
            for (int q = 0; q < 8; ++q)
                fk[r][q] = __builtin_fmaf(-2.0f, acc[r][q], sqi) + sj[q];
        }
    }

    float minr[RPB];
#pragma unroll
    for (int r = 0; r < RPB; ++r) {
        float mn = fk[r][0];
#pragma unroll
        for (int q = 1; q < 8; ++q) mn = fminf(mn, fk[r][q]);
        minr[r] = mn;
        mL[r][wv][lane] = mn;
    }
    if (tid < RPB) cntL[tid] = 0;
    __syncthreads();

    {
        float mn = mL[wv][0][lane];
#pragma unroll
        for (int s = 1; s < 8; ++s) mn = fminf(mn, mL[wv][s][lane]);
        float v32 = mn;
#pragma unroll
        for (int k = 2; k <= 64; k <<= 1) {
#pragma unroll
            for (int j = k >> 1; j >= 1; j >>= 1) {
                float pv = __shfl_xor(v32, j);
                bool keepMin = (((lane & j) == 0) == ((lane & k) == 0));
                float lo = v32 < pv ? v32 : pv;
                float hi = v32 < pv ? pv : v32;
                v32 = keepMin ? lo : hi;
            }
        }
        if (lane == 17) tL[wv] = v32;
    }
    __syncthreads();

    {
#pragma unroll
        for (int r = 0; r < RPB; ++r) {
            float Tr = tL[r];
            if (minr[r] <= Tr) {
#pragma unroll
                for (int q = 0; q < 8; ++q) {
                    if (fk[r][q] <= Tr) {
                        int jq = ((q >> 2) << 11) + j0 + (q & 3);
                        u32 s = atomicAdd(&cntL[r], 1u);
                        if (s < 64) bufL[r][s] = ((u64)fkey(fk[r][q]) << 32) | (u32)jq;
                    }
                }
            }
        }
    }
    __syncthreads();

    {
        const int w = wv;
        const u32 cnt = cntL[w];
        const int row = b * N_ + i0 + w;
        if (cnt <= 64) {
            u64 myc = (lane < (int)cnt) ? bufL[w][lane] : ~0ull;
            u32 rank = 0;
            for (u32 m = 0; m < cnt; ++m) {
                u64 o = bufL[w][m];
                rank += (o < myc) ? 1u : 0u;
            }
            if (lane < (int)cnt && rank <= 16 && (rank & 1) == 0)
                out[row * KOUT + (rank >> 1)] = (int)((u32)myc & (N_ - 1));
            if (lane < KOUT)
                out[B_ * N_ * KOUT + row * KOUT + lane] = i0 + w;
        } else {
            const float sqw = sqb[i0 + w];
            u64 L0 = ~0ull, L1 = ~0ull, L2 = ~0ull, L3 = ~0ull, L4 = ~0ull, L5 = ~0ull;
#pragma unroll 1
            for (int m = 0; m < 64; ++m) {
                int j = lane + (m << 6);
                float a = 0.0f;
#pragma unroll 1
                for (int c = 0; c < C_; ++c)
                    a = __builtin_fmaf(cenL[c][w], xb[(size_t)c * N_ + j], a);
                float d = __builtin_fmaf(-2.0f, a, sqw) + sqb[j];
                ins6(((u64)fkey(d) << 32) | (u32)j, L0, L1, L2, L3, L4, L5);
            }
            u64 lastPop = 0;
            u32 myw = 0;
#pragma unroll 1
            for (int r = 0; r < KOUT; ++r) {
                u64 a0 = L0, a1 = L1;
#pragma unroll
                for (int off = 32; off >= 1; off >>= 1) {
                    u64 b0 = __shfl_xor(a0, off);
                    u64 b1 = __shfl_xor(a1, off);
                    u64 lo = (a0 < b0) ? a0 : b0;
                    u64 hi = (a0 < b0) ? b0 : a0;
                    u64 m1 = (a1 < b1) ? a1 : b1;
                    a0 = lo;
                    a1 = (hi < m1) ? hi : m1;
                }
                if (lane == r) myw = (u32)a0;
                bool own0 = ((u32)a0 & 63) == (u32)lane;
                bool own1 = ((u32)a1 & 63) == (u32)lane;
                if (own0) { lastPop = a0; L0 = L1; L1 = L2; L2 = L3; L3 = L4; L4 = L5; L5 = ~0ull; }
                if (own1) { lastPop = a1; L0 = L1; L1 = L2; L2 = L3; L3 = L4; L4 = L5; L5 = ~0ull; }
                if ((own0 || own1) && L1 == ~0ull && r < KOUT - 1) {
                    L0 = L1 = L2 = L3 = L4 = L5 = ~0ull;
#pragma unroll 1
                    for (int m = 0; m < 64; ++m) {
                        int j = lane + (m << 6);
                        float a = 0.0f;
#pragma unroll 1
                        for (int c = 0; c < C_; ++c)
                            a = __builtin_fmaf(cenL[c][w], xb[(size_t)c * N_ + j], a);
                        float d = __builtin_fmaf(-2.0f, a, sqw) + sqb[j];
                        u64 kk = ((u64)fkey(d) << 32) | (u32)j;
                        if (kk > lastPop) ins6(kk, L0, L1, L2, L3, L4, L5);
                    }
                }
            }
            if (lane < KOUT) {
                int o = row * KOUT + lane;
                out[o] = (int)(myw & (N_ - 1));
                out[B_ * N_ * KOUT + o] = i0 + w;
            }
        }
    }
}

// ------- mode-1 prep5: coalesced loads + LDS transpose + coalesced writes -------
// (R11/R14/R16/R18-proven.) 256 thr / 64 points, st[64][33] staging, LINEAR writes.

__global__ __launch_bounds__(256) void prep5_kernel(const float* __restrict__ x,
                                                    float* __restrict__ ws) {
#pragma clang fp contract(off)
    __shared__ float st[64][33];
    const int tid = threadIdx.x;
    const int l = tid & 63;
    const int sub = tid >> 6;
    const int chunk0 = blockIdx.x * 64;
    const int gid = chunk0 + l;
    const int b = gid >> 12, n = gid & (N_ - 1);
    const float* xp = x + (size_t)b * (C_ * N_) + n;

    float v[8];
#pragma unroll
    for (int e = 0; e < 8; ++e) v[e] = xp[(size_t)(8 * sub + e) * N_];
#pragma unroll
    for (int e = 0; e < 8; ++e) st[l][8 * sub + e] = v[e];
    __syncthreads();

    float* xT = ws + XT_OFF_F32 + (size_t)chunk0 * 32;
#pragma unroll
    for (int k = 0; k < 8; ++k) {
        int f = k * 256 + tid;
        xT[f] = st[f >> 5][f & 31];
    }
    u32* xbf = (u32*)ws + XP_OFF_U32 + (size_t)chunk0 * 16;
#pragma unroll
    for (int k = 0; k < 4; ++k) {
        int g = k * 256 + tid;
        int nl = g >> 4, p = g & 15;
        xbf[g] = rne_bf16(st[nl][2 * p]) | (rne_bf16(st[nl][2 * p + 1]) << 16);
    }
    if (sub == 0) {
        float w[C_];
#pragma unroll
        for (int c = 0; c < C_; ++c) { float t = st[l][c]; w[c] = t * t; }
        float r[8];
#pragma unroll
        for (int j = 0; j < 8; ++j) r[j] = w[j];
#pragma unroll
        for (int i = 8; i < 32; i += 8) {
#pragma unroll
            for (int j = 0; j < 8; ++j) r[j] = r[j] + w[i + j];
        }
        ws[gid] = ((r[0] + r[1]) + (r[2] + r[3])) + ((r[4] + r[5]) + (r[6] + r[7]));
    }
}

// ------- mode-1 knn v6 (R16/R18-proven best, 77.8us): 64-row blocks, 4 MFMA ------
// per B-load, si hoisted out of pass loops, unroll 2, LDS-broadcast rank.
// Knob space mapped: unroll {4✗,8✗}, shfl-rank ✗ (dyn-idx shfl = ds_bpermute),
// subsample-T ✗ (R7 storm), direct-x verify ✗ (32 lines/candidate), coop
// fusion ✗ (grid.sync deadlock risk under graph capture). This is the floor
// of this structure with the safe lever set exhausted.

__global__ __launch_bounds__(TPB3, 2) void knn_kernel_v6(const float* __restrict__ x,
                                                         const float* __restrict__ ws,
                                                         int* __restrict__ out) {
#pragma clang fp contract(off)
    __shared__ float cenL[C_][RPB4];     // 8 KB exact centers (verify + fallback)
    __shared__ float mL[RPB4][64];       // 16 KB per-(row, partition) min upper bound
    __shared__ u64 bufL[RPB4][64];       // 32 KB candidate buffers
    __shared__ u32 cntL[RPB4];
    __shared__ float tL[RPB4];

    const int tid = threadIdx.x;
    const int b = blockIdx.x & 7;               // XCD-batch affinity (proven R2)
    const int i0 = (blockIdx.x >> 3) * RPB4;
    const float* xb = x + (size_t)b * (C_ * N_);
    const float* sqb = ws + b * N_;
    const u32* xbfU = (const u32*)ws + XP_OFF_U32 + (size_t)b * N_ * 16;
    const float* xTb = ws + XT_OFF_F32 + (size_t)b * N_ * 32;

    {   // 2048 center entries, 512 threads, 4 each
#pragma unroll
        for (int k = 0; k < 4; ++k) {
            int t2 = tid + k * 512;
            cenL[t2 >> 6][t2 & 63] = xb[(size_t)(t2 >> 6) * N_ + (i0 + (t2 & 63))];
        }
    }
    if (tid < RPB4) cntL[tid] = 0;
    __syncthreads();

    const int w = tid >> 6, l = tid & 63;
    const int col = l & 15, grp = l >> 4;

    // Four A-frags (row groups h: i0+16h .. i0+16h+15). A/B use identical
    // lane->(n,k) addressing so any within-frag k-relabel cancels (R5-proven).
    short8 af0 = __builtin_bit_cast(short8,
        *(const uint4*)(xbfU + (size_t)(i0 + col) * 16 + grp * 4));
    short8 af1 = __builtin_bit_cast(short8,
        *(const uint4*)(xbfU + (size_t)(i0 + 16 + col) * 16 + grp * 4));
    short8 af2 = __builtin_bit_cast(short8,
        *(const uint4*)(xbfU + (size_t)(i0 + 32 + col) * 16 + grp * 4));
    short8 af3 = __builtin_bit_cast(short8,
        *(const uint4*)(xbfU + (size_t)(i0 + 48 + col) * 16 + grp * 4));
    const f32x4 z4 = {0.0f, 0.0f, 0.0f, 0.0f};

    // index [4h+q] <-> row i0 + 16h + grp*4 + q
    float siU[16], siL[16];
#pragma unroll
    for (int h = 0; h < 4; ++h)
#pragma unroll
        for (int q = 0; q < 4; ++q) {
            float s0 = sqb[i0 + 16 * h + grp * 4 + q];
            siU[4 * h + q] = __builtin_fmaf(SLC2, s0, s0) + SLA2;
            siL[4 * h + q] = __builtin_fmaf(-SLC2, s0, s0) - SLA2;
        }

    const int jw = w << 9;                      // wave's 512-j span base
    const u32* bptr = xbfU + (size_t)(jw + col) * 16 + grp * 4;
    const float* sjp = sqb + jw + col;

    // ---- pass 1: per-(row, partition) minima over ALL 32 tiles (R7 lesson:
    // full pass = proven-tight T). tmin tracks min_t fma(-2,c,sjU_t); siU
    // added after the loop. Partition = (wave, col-pair): 64 disjoint x 64 j.
    float tmin[16];
#pragma unroll
    for (int q = 0; q < 16; ++q) tmin[q] = 3.4e38f;
#pragma unroll 2
    for (int t = 0; t < 32; ++t) {
        uint4 buv = *(const uint4*)(bptr + (size_t)t * 256);
        float sj = sjp[t * 16];
        float sjU = __builtin_fmaf(SLC2, sj, sj);
        short8 bf = __builtin_bit_cast(short8, buv);
        f32x4 c0 = __builtin_amdgcn_mfma_f32_16x16x32_bf16(af0, bf, z4, 0, 0, 0);
        f32x4 c1 = __builtin_amdgcn_mfma_f32_16x16x32_bf16(af1, bf, z4, 0, 0, 0);
        f32x4 c2 = __builtin_amdgcn_mfma_f32_16x16x32_bf16(af2, bf, z4, 0, 0, 0);
        f32x4 c3 = __builtin_amdgcn_mfma_f32_16x16x32_bf16(af3, bf, z4, 0, 0, 0);
#pragma unroll
        for (int q = 0; q < 4; ++q) {
            tmin[q]      = fminf(tmin[q],      __builtin_fmaf(-2.0f, c0[q], sjU));
            tmin[4 + q]  = fminf(tmin[4 + q],  __builtin_fmaf(-2.0f, c1[q], sjU));
            tmin[8 + q]  = fminf(tmin[8 + q],  __builtin_fmaf(-2.0f, c2[q], sjU));
            tmin[12 + q] = fminf(tmin[12 + q], __builtin_fmaf(-2.0f, c3[q], sjU));
        }
    }
#pragma unroll
    for (int q = 0; q < 16; ++q) {
        tmin[q] += siU[q];
        tmin[q] = fminf(tmin[q], __shfl_xor(tmin[q], 1));
    }
    if (!(l & 1)) {
        const int cp = (w << 3) + (col >> 1);
#pragma unroll
        for (int h = 0; h < 4; ++h)
#pragma unroll
            for (int q = 0; q < 4; ++q)
                mL[16 * h + grp * 4 + q][cp] = tmin[4 * h + q];
    }
    __syncthreads();

    // ---- T[row] = 18th-smallest partition min; wave w sorts rows 8w..8w+7
    // (8-way interleaved bitonic; sorted[17] lands in lane 17).
    {
        float v[8];
#pragma unroll
        for (int s = 0; s < 8; ++s) v[s] = mL[8 * w + s][l];
#pragma unroll
        for (int k = 2; k <= 64; k <<= 1) {
#pragma unroll
            for (int j = k >> 1; j >= 1; j >>= 1) {
                bool keepMin = (((l & j) == 0) == ((l & k) == 0));
#pragma unroll
                for (int s = 0; s < 8; ++s) {
                    float pv = __shfl_xor(v[s], j);
                    float lo = v[s] < pv ? v[s] : pv;
                    float hi = v[s] < pv ? pv : v[s];
                    v[s] = keepMin ? lo : hi;
                }
            }
        }
        if (l == 17) {
#pragma unroll
            for (int s = 0; s < 8; ++s) tL[8 * w + s] = v[s];
        }
    }
    __syncthreads();

    // ---- pass 2 (all 32 tiles): admit j if fma(-2,c,sjL) <= TU-siL.
    float TUp[16];
#pragma unroll
    for (int h = 0; h < 4; ++h)
#pragma unroll
        for (int q = 0; q < 4; ++q)
            TUp[4 * h + q] = tL[16 * h + grp * 4 + q] - siL[4 * h + q];
    const int jc = jw + col;
#pragma unroll 2
    for (int t = 0; t < 32; ++t) {
        uint4 buv = *(const uint4*)(bptr + (size_t)t * 256);
        float sj = sjp[t * 16];
        float sjL = __builtin_fmaf(-SLC2, sj, sj);
        short8 bf = __builtin_bit_cast(short8, buv);
        f32x4 c0 = __builtin_amdgcn_mfma_f32_16x16x32_bf16(af0, bf, z4, 0, 0, 0);
        f32x4 c1 = __builtin_amdgcn_mfma_f32_16x16x32_bf16(af1, bf, z4, 0, 0, 0);
        f32x4 c2 = __builtin_amdgcn_mfma_f32_16x16x32_bf16(af2, bf, z4, 0, 0, 0);
        f32x4 c3 = __builtin_amdgcn_mfma_f32_16x16x32_bf16(af3, bf, z4, 0, 0, 0);
        const int jq = jc + (t << 4);
#pragma unroll
        for (int q = 0; q < 4; ++q) {
            float v0 = __builtin_fmaf(-2.0f, c0[q], sjL);
            if (v0 <= TUp[q]) {
                const int rr = grp * 4 + q;
                u32 s = atomicAdd(&cntL[rr], 1u);
                if (s < 64) bufL[rr][s] =
                    ((u64)__float_as_uint(v0 + siL[q]) << 32) | (u32)jq;
            }
            float v1 = __builtin_fmaf(-2.0f, c1[q], sjL);
            if (v1 <= TUp[4 + q]) {
                const int rr = 16 + grp * 4 + q;
                u32 s = atomicAdd(&cntL[rr], 1u);
                if (s < 64) bufL[rr][s] =
                    ((u64)__float_as_uint(v1 + siL[4 + q]) << 32) | (u32)jq;
            }
            float v2 = __builtin_fmaf(-2.0f, c2[q], sjL);
            if (v2 <= TUp[8 + q]) {
                const int rr = 32 + grp * 4 + q;
                u32 s = atomicAdd(&cntL[rr], 1u);
                if (s < 64) bufL[rr][s] =
                    ((u64)__float_as_uint(v2 + siL[8 + q]) << 32) | (u32)jq;
            }
            float v3 = __builtin_fmaf(-2.0f, c3[q], sjL);
            if (v3 <= TUp[12 + q]) {
                const int rr = 48 + grp * 4 + q;
                u32 s = atomicAdd(&cntL[rr], 1u);
                if (s < 64) bufL[rr][s] =
                    ((u64)__float_as_uint(v3 + siL[12 + q]) << 32) | (u32)jq;
            }
        }
    }
    __syncthreads();

    // ---- verify + rank (proven) + band-check; wave w: rows 8w..8w+7.
#pragma unroll 1
    for (int sub = 0; sub < 8; ++sub) {
        const int rr = 8 * w + sub;
        const int row = b * N_ + i0 + rr;
        const u32 cnt = cntL[rr];
        const float sqi = sqb[i0 + rr];
        bool ok = (cnt >= 18u && cnt <= 64u);
        u64 myc = ~0ull;
        bool band = true;
        if (ok && l < (int)cnt) {
            u64 e = bufL[rr][l];
            int jq = (int)(u32)e;
            float lov = __uint_as_float((u32)(e >> 32));
            const float* xj = xTb + (size_t)jq * 32;    // 128 B contiguous
            float a = 0.0f;
#pragma unroll
            for (int c = 0; c < C_; ++c)
                a = __builtin_fmaf(cenL[c][rr], xj[c], a);   // exact chain, c ascending
            float d = __builtin_fmaf(-2.0f, a, sqi) + sqb[jq];
            float sl = __builtin_fmaf(sqi + sqb[jq], SLC2, SLA2);
            float eps = 0.01f + 1e-3f * fabsf(d);
            band = (d + eps >= lov) && (d <= lov + 2.0f * sl + eps);
            myc = ((u64)fkey(d) << 32) | (u32)jq;
        }
        if (__any(!band)) ok = false;           // bounds invalid => exact fallback
        if (ok) {
            if (l < (int)cnt) bufL[rr][l] = myc;     // same-wave LDS, in-order
            u32 rank = 0;
            for (u32 m = 0; m < cnt; ++m) {
                u64 o = bufL[rr][m];                 // broadcast read
                rank += (o < myc) ? 1u : 0u;
            }
            if (l < (int)cnt && rank <= 16 && (rank & 1) == 0)
                out[row * KOUT + (rank >> 1)] = (int)((u32)myc & (N_ - 1));
            if (l < KOUT)
                out[B_ * N_ * KOUT + row * KOUT + l] = i0 + rr;
        } else {
            // exact R7 scan + pop-2 (proven semantics).
            const float sqw = sqi;
            u64 L0 = ~0ull, L1 = ~0ull, L2 = ~0ull, L3 = ~0ull, L4 = ~0ull, L5 = ~0ull;
#pragma unroll 1
            for (int m = 0; m < 64; ++m) {
                int j = l + (m << 6);
                float a = 0.0f;
#pragma unroll
                for (int c = 0; c < C_; ++c)
                    a = __builtin_fmaf(cenL[c][rr], xb[(size_t)c * N_ + j], a);
                float d = __builtin_fmaf(-2.0f, a, sqw) + sqb[j];
                ins6(((u64)fkey(d) << 32) | (u32)j, L0, L1, L2, L3, L4, L5);
            }
            u64 lastPop = 0;
            u32 myw = 0;
#pragma unroll 1
            for (int r = 0; r < KOUT; ++r) {
                u64 a0 = L0, a1 = L1;
#pragma unroll
                for (int off = 32; off >= 1; off >>= 1) {
                    u64 b0 = __shfl_xor(a0, off);
                    u64 b1 = __shfl_xor(a1, off);
                    u64 lo = (a0 < b0) ? a0 : b0;
                    u64 hi = (a0 < b0) ? b0 : a0;
                    u64 m1 = (a1 < b1) ? a1 : b1;
                    a0 = lo;
                    a1 = (hi < m1) ? hi : m1;
                }
                if (l == r) myw = (u32)a0;
                bool own0 = ((u32)a0 & 63) == (u32)l;
                bool own1 = ((u32)a1 & 63) == (u32)l;
                if (own0) { lastPop = a0; L0 = L1; L1 = L2; L2 = L3; L3 = L4; L4 = L5; L5 = ~0ull; }
                if (own1) { lastPop = a1; L0 = L1; L1 = L2; L2 = L3; L3 = L4; L4 = L5; L5 = ~0ull; }
                if ((own0 || own1) && L1 == ~0ull && r < KOUT - 1) {
                    L0 = L1 = L2 = L3 = L4 = L5 = ~0ull;
#pragma unroll 1
                    for (int m = 0; m < 64; ++m) {
                        int j = l + (m << 6);
                        float a = 0.0f;
#pragma unroll
                        for (int c = 0; c < C_; ++c)
                            a = __builtin_fmaf(cenL[c][rr], xb[(size_t)c * N_ + j], a);
                        float d = __builtin_fmaf(-2.0f, a, sqw) + sqb[j];
                        u64 kk = ((u64)fkey(d) << 32) | (u32)j;
                        if (kk > lastPop) ins6(kk, L0, L1, L2, L3, L4, L5);
                    }
                }
            }
            if (l < KOUT) {
                int o = row * KOUT + l;
                out[o] = (int)(myw & (N_ - 1));
                out[B_ * N_ * KOUT + o] = i0 + rr;
            }
        }
    }
}

extern "C" void kernel_launch(void* const* d_in, const int* in_sizes, int n_in,
                              void* d_out, int out_size, void* d_ws, size_t ws_size,
                              hipStream_t stream) {
    const float* x = (const float*)d_in[0];
    float* ws = (float*)d_ws;
    int* out = (int*)d_out;

    if (ws_size >= NEED_XT_B) {
        hipLaunchKernelGGL(prep5_kernel, dim3(B_ * N_ / 64), dim3(256), 0, stream, x, ws);
        hipLaunchKernelGGL(knn_kernel_v6, dim3(B_ * N_ / RPB4), dim3(TPB3), 0, stream,
                           x, ws, out);
    } else {
        hipLaunchKernelGGL(sq_kernel, dim3(B_ * N_ / 256), dim3(256), 0, stream, x, ws);
        hipLaunchKernelGGL(knn_kernel_old, dim3(B_ * N_ / RPB), dim3(TPB), 0, stream,
                           x, ws, out);
    }
}